// Round 7
// baseline (175.126 us; speedup 1.0000x reference)
//
#include <hip/hip_runtime.h>
#include <math.h>

#define HEADS 4
#define DIMH  128
#define NB    16
#define CIN   512
#define SEQ   1024
#define OTOT  1536
#define KQ    (CIN / 8)

typedef __attribute__((ext_vector_type(8)))  short bf16x8;
typedef __attribute__((ext_vector_type(4)))  short bf16x4;
typedef __attribute__((ext_vector_type(4)))  float f32x4;
typedef __attribute__((ext_vector_type(16))) float f32x16;

#define MFMA16(a,b,c) __builtin_amdgcn_mfma_f32_16x16x32_bf16(a,b,c,0,0,0)
#define MFMA32(a,b,c) __builtin_amdgcn_mfma_f32_32x32x16_bf16(a,b,c,0,0,0)

__device__ __forceinline__ short f2bf(float f) {           // RNE
    unsigned u = __builtin_bit_cast(unsigned, f);
    u = (u + 0x7FFFu + ((u >> 16) & 1u)) >> 16;
    return (short)u;
}
// pack hi16(lo), hi16(hi) -> one dword {hi_bf16, lo_bf16} (truncating bf16)
__device__ __forceinline__ unsigned pk2(float lo, float hi) {
    return __builtin_amdgcn_perm(__builtin_bit_cast(unsigned, hi),
                                 __builtin_bit_cast(unsigned, lo), 0x07060302u);
}
union PF8 { unsigned u[4]; bf16x8 v; };

// async global->LDS, 16B per lane; lds dest = wave-uniform base + lane*16
__device__ __forceinline__ void gll16(const short* g, short* l) {
    __builtin_amdgcn_global_load_lds(
        (const __attribute__((address_space(1))) unsigned*)g,
        (__attribute__((address_space(3))) unsigned*)l,
        16, 0, 0);
}

// ---------- weight convert only: w -> Wb2 [kq][o][8]  (~4.5 MB total, ~2 us) ----------
__global__ __launch_bounds__(256) void convert_w(const float* __restrict__ W,
                                                 short* __restrict__ Wb2) {
    const int kq = blockIdx.y;
    const int o = blockIdx.x * 256 + threadIdx.x;
    float4 v0 = *(const float4*)&W[(size_t)o * CIN + kq * 8];
    float4 v1 = *(const float4*)&W[(size_t)o * CIN + kq * 8 + 4];
    bf16x8 pk = { f2bf(v0.x), f2bf(v0.y), f2bf(v0.z), f2bf(v0.w),
                  f2bf(v1.x), f2bf(v1.y), f2bf(v1.z), f2bf(v1.w) };
    *(bf16x8*)&Wb2[((size_t)kq * OTOT + o) * 8] = pk;
}

// ---------- QKV GEMM, fused fmap conversion ----------
// m97 structure (128x128, BK=32, dbuf LDS).  A (weights) staged bf16 via
// global_load_lds; B (fmap) gathered DIRECTLY from f32 fmap (8 strided,
// wave-coalesced loads / task, issued at K-step top), converted with the same
// RNE f2bf (bit-identical to the old FT2 path), ds_write'd after the MFMA
// block (issue-early / write-late: HBM/L3 latency hides under compute).
// Eliminates the 16.8 MB FT2 write + read and one kernel launch.
// Q -> [bh][s][d]; K -> Kf[bh][c/8][s][8] (+emb); V -> Vf[bh][s/16][d][slot]
__global__ __launch_bounds__(256, 3) void qkv_gemm(
    const short* __restrict__ Wb2, const float* __restrict__ F,
    const float* __restrict__ height, const float* __restrict__ width,
    short* __restrict__ Qo, short* __restrict__ Kfo, short* __restrict__ Vfo)
{
    __shared__ short As[2][4 * 128 * 8];   // [buf][kq-plane][o 128][8]   8 KB/buf
    __shared__ short Bs[2][4 * 128 * 8];   // [buf][kq-plane][s 128][8]   8 KB/buf

    const int L  = blockIdx.x;
    const int x8 = L & 7, m = L >> 3;
    const int g  = x8 + 8 * (m / 12);      // 128 groups = (b, sx) pinned per XCD
    const int oy = m % 12;
    const int b  = g >> 3, sx = g & 7;
    const int o0 = oy * 128, s0 = sx * 128;

    const int t = threadIdx.x, l = t & 63, w = t >> 6;
    const int quad = l >> 4, ln = l & 15;
    const int wrow = (w >> 1) * 64, wcol = (w & 1) * 64;

    // per-wave task split (16 tasks = 8 planes x 2 halves): wave w owns
    // A planes {pa, 2+pa} and B planes {pa, 2+pa}, rows hfw*64 + l
    const int pa = w >> 1, hfw = w & 1;
    float fv0[8], fv1[8];

#define STAGE_ISSUE(ks, buf) { \
    gll16(Wb2 + (((size_t)((ks) * 4 + pa) * OTOT) + o0 + hfw * 64 + l) * 8, \
          &As[buf][(pa * 128 + hfw * 64) * 8]); \
    gll16(Wb2 + (((size_t)((ks) * 4 + 2 + pa) * OTOT) + o0 + hfw * 64 + l) * 8, \
          &As[buf][((2 + pa) * 128 + hfw * 64) * 8]); \
    const float* f0 = F + ((size_t)b * CIN + ((ks) * 4 + pa) * 8) * SEQ + (s0 + hfw * 64 + l); \
    const float* f1 = F + ((size_t)b * CIN + ((ks) * 4 + 2 + pa) * 8) * SEQ + (s0 + hfw * 64 + l); \
    _Pragma("unroll") for (int i = 0; i < 8; ++i) fv0[i] = f0[(size_t)i * SEQ]; \
    _Pragma("unroll") for (int i = 0; i < 8; ++i) fv1[i] = f1[(size_t)i * SEQ]; }

#define STAGE_WRITE(buf) { \
    bf16x8 pk0 = { f2bf(fv0[0]), f2bf(fv0[1]), f2bf(fv0[2]), f2bf(fv0[3]), \
                   f2bf(fv0[4]), f2bf(fv0[5]), f2bf(fv0[6]), f2bf(fv0[7]) }; \
    bf16x8 pk1 = { f2bf(fv1[0]), f2bf(fv1[1]), f2bf(fv1[2]), f2bf(fv1[3]), \
                   f2bf(fv1[4]), f2bf(fv1[5]), f2bf(fv1[6]), f2bf(fv1[7]) }; \
    *(bf16x8*)&Bs[buf][(pa * 128 + hfw * 64 + l) * 8] = pk0; \
    *(bf16x8*)&Bs[buf][((2 + pa) * 128 + hfw * 64 + l) * 8] = pk1; }

    f32x4 acc[4][4] = {};

    STAGE_ISSUE(0, 0);
    STAGE_WRITE(0);
    __syncthreads();                        // drains gll16 (vmcnt) + ds_writes

    for (int ks = 0; ks < 16; ++ks) {
        const int cb = ks & 1;
        if (ks < 15) STAGE_ISSUE(ks + 1, cb ^ 1);  // A async; B f32 -> regs (in flight)
        const short* Ab = &As[cb][0];
        const short* Bb = &Bs[cb][0];
        bf16x8 af[4], bfr[4];
        #pragma unroll
        for (int i = 0; i < 4; ++i)
            af[i]  = *(const bf16x8*)&Ab[((size_t)quad * 128 + wrow + i * 16 + ln) * 8];
        #pragma unroll
        for (int j = 0; j < 4; ++j)
            bfr[j] = *(const bf16x8*)&Bb[((size_t)quad * 128 + wcol + j * 16 + ln) * 8];
        #pragma unroll
        for (int i = 0; i < 4; ++i)
            #pragma unroll
            for (int j = 0; j < 4; ++j)
                acc[i][j] = MFMA16(af[i], bfr[j], acc[i][j]);
        if (ks < 15) STAGE_WRITE(cb ^ 1);          // convert + LDS write after compute
        __syncthreads();
    }

    const int sec = o0 >> 9;
    const int h   = (o0 >> 7) & 3;
    const size_t bh = (size_t)b * HEADS + h;

    if (sec == 0) {
        const float qs = 0.08838834764831845f * 1.4426950408889634f; // scale*log2(e)
        #pragma unroll
        for (int ti = 0; ti < 4; ++ti) {
            int d = wrow + ti * 16 + quad * 4;
            #pragma unroll
            for (int tj = 0; tj < 4; ++tj) {
                int s = s0 + wcol + tj * 16 + ln;
                f32x4 a = acc[ti][tj];
                bf16x4 pk4 = { f2bf(a[0]*qs), f2bf(a[1]*qs), f2bf(a[2]*qs), f2bf(a[3]*qs) };
                *(bf16x4*)&Qo[(bh * SEQ + s) * DIMH + d] = pk4;
            }
        }
    } else if (sec == 1) {
        #pragma unroll
        for (int ti = 0; ti < 4; ++ti) {
            int d = wrow + ti * 16 + quad * 4;
            #pragma unroll
            for (int tj = 0; tj < 4; ++tj) {
                int s = s0 + wcol + tj * 16 + ln;
                float4 hv = *(const float4*)&height[(size_t)(s >> 5) * DIMH + d];
                float4 wv = *(const float4*)&width[(size_t)(s & 31) * DIMH + d];
                f32x4 a = acc[ti][tj];
                bf16x4 pk4 = { f2bf(a[0] + hv.x + wv.x), f2bf(a[1] + hv.y + wv.y),
                               f2bf(a[2] + hv.z + wv.z), f2bf(a[3] + hv.w + wv.w) };
                *(bf16x4*)&Kfo[(((size_t)bh * 16 + (d >> 3)) * SEQ + s) * 8 + (d & 7)] = pk4;
            }
        }
    } else {
        const int slot = ((ln >> 2) & 1) * 8 + (ln & 3) + ((ln >> 3) << 2);
        #pragma unroll
        for (int ti = 0; ti < 4; ++ti) {
            int d = wrow + ti * 16 + quad * 4;
            #pragma unroll
            for (int tj = 0; tj < 4; ++tj) {
                int s = s0 + wcol + tj * 16 + ln;
                size_t vb = (((size_t)bh * 64 + (s >> 4)) * DIMH) * 16 + slot;
                f32x4 a = acc[ti][tj];
                #pragma unroll
                for (int r = 0; r < 4; ++r)
                    Vfo[vb + (size_t)(d + r) * 16] = f2bf(a[r]);
            }
        }
    }
}

// ---------- flash attention: quad-buffered K, stage distance +3, barrier per 2 tiles ----------
#define BQ 128
#define BJ 64
#define KSTR 136   // conflict-free stride (SQ_LDS_BANK_CONFLICT = 0)

// entry invariant at iter ti: S0/S1 = S(ti); slots hold K(ti+1), K(ti+2), K(ti+3*)
#define ATTN_ITER(ti, DO_QK, DO_PRE, DO_BAR)                                        \
{                                                                                   \
    const int rd = (((ti) + 1) & 3) * (BJ * KSTR);                                  \
    const int wr = (((ti) + 3) & 3) * (BJ * KSTR);                                  \
    const short* vp0 = Vlane + (size_t)((ti) * 4) * (DIMH * 16);                    \
    bf16x8 vr[4][4];                                                                \
    _Pragma("unroll") for (int gi = 0; gi < 2; ++gi)                                \
      _Pragma("unroll") for (int dc = 0; dc < 4; ++dc)                              \
        vr[gi][dc] = *(const bf16x8*)(vp0 + (size_t)gi * (DIMH * 16) + dc * 32 * 16);\
    int4 kreg[4];                                                                   \
    if (DO_PRE) {                                                                   \
        _Pragma("unroll") for (int p = 0; p < 4; ++p)                               \
            kreg[p] = *(const int4*)(Kg + ((size_t)(p * 4 + w) * SEQ + ((ti) + 3) * BJ + l) * 8); \
    }                                                                               \
    PF8 pf[4];                                                                      \
    _Pragma("unroll") for (int g = 0; g < 4; ++g) {                                 \
        const f32x16& Sh = (g & 2) ? S1 : S0;                                       \
        const int kk = g & 1;                                                       \
        _Pragma("unroll") for (int mm = 0; mm < 4; ++mm) {                          \
            float ea = __builtin_amdgcn_exp2f(Sh[kk * 8 + 2 * mm]);                 \
            float eb = __builtin_amdgcn_exp2f(Sh[kk * 8 + 2 * mm + 1]);             \
            psum += ea + eb;                                                        \
            pf[g].u[mm] = pk2(ea, eb);                                              \
        }                                                                           \
    }                                                                               \
    _Pragma("unroll") for (int gi = 2; gi < 4; ++gi)                                \
      _Pragma("unroll") for (int dc = 0; dc < 4; ++dc)                              \
        vr[gi][dc] = *(const bf16x8*)(vp0 + (size_t)gi * (DIMH * 16) + dc * 32 * 16);\
    if (DO_QK) {                                                                    \
        S0 = (f32x16){}; S1 = (f32x16){};                                           \
        _Pragma("unroll") for (int kc = 0; kc < 8; ++kc) {                          \
            bf16x8 k0 = *(const bf16x8*)&Ks[rd + c31 * KSTR + kc * 16 + h * 8];     \
            bf16x8 k1 = *(const bf16x8*)&Ks[rd + (32 + c31) * KSTR + kc * 16 + h * 8]; \
            S0 = MFMA32(k0, qf[kc], S0);                                            \
            S1 = MFMA32(k1, qf[kc], S1);                                            \
        }                                                                           \
    }                                                                               \
    _Pragma("unroll") for (int g = 0; g < 4; ++g)                                   \
        _Pragma("unroll") for (int dc = 0; dc < 4; ++dc)                            \
            O[dc] = MFMA32(vr[g][dc], pf[g].v, O[dc]);                              \
    if (DO_PRE) {                                                                   \
        _Pragma("unroll") for (int p = 0; p < 4; ++p)                               \
            *(int4*)&Ks[wr + l * KSTR + (p * 4 + w) * 8] = kreg[p];                 \
    }                                                                               \
    if (DO_BAR) __syncthreads();                                                    \
}

__global__ __launch_bounds__(256, 2) void attn(
    const short* __restrict__ Q, const short* __restrict__ Kf,
    const short* __restrict__ Vf, float* __restrict__ out)
{
    __shared__ short Ks[4 * BJ * KSTR];   // quad-buffered K tiles [j][c]

    const int t = threadIdx.x, l = t & 63, w = t >> 6;
    const int h = l >> 5, c31 = l & 31;

    const int L = blockIdx.x;
    const int x = L & 7, inner = L >> 3;          // XCD swizzle: same bh -> same XCD
    const int bh = x * 8 + (inner >> 3);
    const int q0 = (inner & 7) * BQ;
    const size_t obase = (size_t)bh * DIMH * SEQ;

    // Q B-fragments (n = i = q0+w*32+c31, k = c = kc*16 + h*8 + 0..7)
    bf16x8 qf[8];
    {
        const short* Qp = Q + ((size_t)bh * SEQ + (q0 + w * 32 + c31)) * DIMH + h * 8;
        #pragma unroll
        for (int kc = 0; kc < 8; ++kc)
            qf[kc] = *(const bf16x8*)(Qp + kc * 16);
    }

    const short* Kg = Kf + (size_t)bh * 16 * SEQ * 8;             // [cg][s][8]
    const short* Vlane = Vf + (size_t)bh * 64 * (DIMH * 16) + (c31 * 16 + h * 8);

    f32x16 O[4] = {};
    float psum = 0.f;

    // prologue: stage K(0)->slot0, K(1)->slot1, K(2)->slot2
    {
        int4 k0[4], k1[4], k2[4];
        #pragma unroll
        for (int p = 0; p < 4; ++p) {
            k0[p] = *(const int4*)(Kg + ((size_t)(p * 4 + w) * SEQ + l) * 8);
            k1[p] = *(const int4*)(Kg + ((size_t)(p * 4 + w) * SEQ + BJ + l) * 8);
            k2[p] = *(const int4*)(Kg + ((size_t)(p * 4 + w) * SEQ + 2 * BJ + l) * 8);
        }
        #pragma unroll
        for (int p = 0; p < 4; ++p) {
            *(int4*)&Ks[l * KSTR + (p * 4 + w) * 8] = k0[p];
            *(int4*)&Ks[1 * (BJ * KSTR) + l * KSTR + (p * 4 + w) * 8] = k1[p];
            *(int4*)&Ks[2 * (BJ * KSTR) + l * KSTR + (p * 4 + w) * 8] = k2[p];
        }
    }
    __syncthreads();

    // S(0) from slot0
    f32x16 S0 = {}, S1 = {};
    #pragma unroll
    for (int kc = 0; kc < 8; ++kc) {
        bf16x8 k0 = *(const bf16x8*)&Ks[c31 * KSTR + kc * 16 + h * 8];
        bf16x8 k1 = *(const bf16x8*)&Ks[(32 + c31) * KSTR + kc * 16 + h * 8];
        S0 = MFMA32(k0, qf[kc], S0);
        S1 = MFMA32(k1, qf[kc], S1);
    }
    __syncthreads();   // all waves done reading slot0 before iter1 overwrites it

    // iters 0..11: full pipeline, barrier at end of odd iters only
    for (int p = 0; p < 6; ++p) {
        const int t0 = 2 * p;
        ATTN_ITER(t0,     true, true, false);
        ATTN_ITER(t0 + 1, true, true, true);
    }
    ATTN_ITER(12, true, true,  false);   // stages K(15), last stage
    ATTN_ITER(13, true, false, true);    // barrier covers K(15) write -> read at 14
    ATTN_ITER(14, true, false, false);
    ATTN_ITER(15, false, false, false);

    // row sum: this lane holds half the j's for row i=c31; other half in lane^32
    psum += __shfl_xor(psum, 32);
    float linv = 1.0f / psum;

    #pragma unroll
    for (int dc = 0; dc < 4; ++dc)
        #pragma unroll
        for (int r = 0; r < 16; ++r) {
            int d = dc * 32 + (r & 3) + 8 * (r >> 2) + 4 * h;
            out[obase + (size_t)d * SEQ + q0 + w * 32 + c31] = O[dc][r] * linv;
        }
}

extern "C" void kernel_launch(void* const* d_in, const int* in_sizes, int n_in,
                              void* d_out, int out_size, void* d_ws, size_t ws_size,
                              hipStream_t stream) {
    const float* fmap   = (const float*)d_in[0];
    const float* w_qkv  = (const float*)d_in[1];
    const float* height = (const float*)d_in[2];
    const float* width  = (const float*)d_in[3];
    float* outp = (float*)d_out;

    const size_t n_w   = (size_t)OTOT * CIN;
    const size_t n_qkv = (size_t)NB * HEADS * SEQ * DIMH;

    short* Wb2 = (short*)d_ws;
    short* Qb  = Wb2 + n_w;
    short* Kfb = Qb + n_qkv;
    short* Vfb = Kfb + n_qkv;

    convert_w<<<dim3(6, KQ), 256, 0, stream>>>(w_qkv, Wb2);
    qkv_gemm<<<dim3(8 * 12 * NB), 256, 0, stream>>>(
        Wb2, fmap, height, width, Qb, Kfb, Vfb);
    attn<<<dim3(NB * HEADS * (SEQ / BQ)), 256, 0, stream>>>(Qb, Kfb, Vfb, outp);
}

// Round 8
// 171.933 us; speedup vs baseline: 1.0186x; 1.0186x over previous
//
#include <hip/hip_runtime.h>
#include <math.h>

#define HEADS 4
#define DIMH  128
#define NB    16
#define CIN   512
#define SEQ   1024
#define OTOT  1536
#define KQ    (CIN / 8)

typedef __attribute__((ext_vector_type(8)))  short bf16x8;
typedef __attribute__((ext_vector_type(4)))  short bf16x4;
typedef __attribute__((ext_vector_type(4)))  float f32x4;
typedef __attribute__((ext_vector_type(16))) float f32x16;

#define MFMA16(a,b,c) __builtin_amdgcn_mfma_f32_16x16x32_bf16(a,b,c,0,0,0)
#define MFMA32(a,b,c) __builtin_amdgcn_mfma_f32_32x32x16_bf16(a,b,c,0,0,0)

__device__ __forceinline__ short f2bf(float f) {           // RNE
    unsigned u = __builtin_bit_cast(unsigned, f);
    u = (u + 0x7FFFu + ((u >> 16) & 1u)) >> 16;
    return (short)u;
}
// pack hi16(lo), hi16(hi) -> one dword {hi_bf16, lo_bf16} (truncating bf16)
__device__ __forceinline__ unsigned pk2(float lo, float hi) {
    return __builtin_amdgcn_perm(__builtin_bit_cast(unsigned, hi),
                                 __builtin_bit_cast(unsigned, lo), 0x07060302u);
}
union PF8 { unsigned u[4]; bf16x8 v; };

// async global->LDS, 16B per lane; lds dest = wave-uniform base + lane*16
__device__ __forceinline__ void gll16(const short* g, short* l) {
    __builtin_amdgcn_global_load_lds(
        (const __attribute__((address_space(1))) unsigned*)g,
        (__attribute__((address_space(3))) unsigned*)l,
        16, 0, 0);
}

// ---------- merged converts: fmap -> FT2 [b][kq][s][8], w -> Wb2 [kq][o][8] ----------
__global__ __launch_bounds__(256) void convert_all(const float* __restrict__ F,
                                                   const float* __restrict__ W,
                                                   short* __restrict__ FT2,
                                                   short* __restrict__ Wb2) {
    const int kq = blockIdx.y;
    if (blockIdx.z == NB) {                       // weight part: x in [0,6)
        const int o = blockIdx.x * 256 + threadIdx.x;
        float4 v0 = *(const float4*)&W[(size_t)o * CIN + kq * 8];
        float4 v1 = *(const float4*)&W[(size_t)o * CIN + kq * 8 + 4];
        bf16x8 pk = { f2bf(v0.x), f2bf(v0.y), f2bf(v0.z), f2bf(v0.w),
                      f2bf(v1.x), f2bf(v1.y), f2bf(v1.z), f2bf(v1.w) };
        *(bf16x8*)&Wb2[((size_t)kq * OTOT + o) * 8] = pk;
        return;
    }
    if (blockIdx.x >= 4) return;                  // fmap part: x in [0,4)
    const int s = blockIdx.x * 256 + threadIdx.x;
    const int b = blockIdx.z;
    const float* src = F + ((size_t)b * CIN + kq * 8) * SEQ + s;
    float v[8];
    #pragma unroll
    for (int i = 0; i < 8; ++i) v[i] = src[(size_t)i * SEQ];
    bf16x8 pk = { f2bf(v[0]), f2bf(v[1]), f2bf(v[2]), f2bf(v[3]),
                  f2bf(v[4]), f2bf(v[5]), f2bf(v[6]), f2bf(v[7]) };
    *(bf16x8*)&FT2[(((size_t)b * KQ + kq) * SEQ + s) * 8] = pk;
}

// ---------- QKV GEMM: 256x128 tile (oy-pair), BK=32, dbuf LDS via global_load_lds ----------
// B tiles depend only on (b,sx,ks) -- all oy share them.  Each block computes TWO
// 128x128 outputs (oy = yy and yy+6) from ONE B-staging: 32 MFMA per barrier (2x
// amortization of the vmcnt-drain stall), FT2 L3-demand halved, grid 1536 -> 768
// = exactly 3 blocks/CU x 256 CU = ONE dispatch round, no tail.
// LDS 48 KB: As 2buf x 2slice x 4plane x 128 x 8; Bs 2buf x 4plane x 128 x 8.
// acc = 2x4x4 f32x4 = 128 AGPRs; ~64 arch VGPRs.  3 blocks/CU (LDS-capped).
// Q -> [bh][s][d]; K -> Kf[bh][c/8][s][8] (+emb); V -> Vf[bh][s/16][d][slot]
__global__ __launch_bounds__(256, 3) void qkv_gemm(
    const short* __restrict__ Wb2, const short* __restrict__ FT2,
    const float* __restrict__ height, const float* __restrict__ width,
    short* __restrict__ Qo, short* __restrict__ Kfo, short* __restrict__ Vfo)
{
    __shared__ short As[2][2 * 4 * 128 * 8];   // [buf][slice*4+plane][row][8]  16 KB/buf
    __shared__ short Bs[2][4 * 128 * 8];       // [buf][plane][row][8]           8 KB/buf

    const int L  = blockIdx.x;
    const int x8 = L & 7, m = L >> 3;          // m in 0..95
    const int g  = x8 + 8 * (m / 6);           // 128 groups = (b, sx) pinned per XCD
    const int yy = m % 6;                      // oy pair: {yy, yy+6}
    const int b  = g >> 3, sx = g & 7;
    const int s0 = sx * 128;

    const int t = threadIdx.x, l = t & 63, w = t >> 6;
    const int quad = l >> 4, ln = l & 15;
    const int wrow = (w >> 1) * 64, wcol = (w & 1) * 64;

    // 24 wave-tasks per K-step: A = 2 slices x 4 planes x 2 halves (16),
    // B = 4 planes x 2 halves (8).  6 gll16 per wave.
#define STAGE(ks, buf) { \
    _Pragma("unroll") for (int r = 0; r < 6; ++r) { \
        const int task = r * 4 + w; \
        if (task < 16) { \
            const int sl = task >> 3, p = (task >> 1) & 3, hf = task & 1; \
            const short* gsrc = Wb2 + (((size_t)((ks) * 4 + p) * OTOT) + (yy + 6 * sl) * 128 + hf * 64 + l) * 8; \
            gll16(gsrc, &As[buf][((sl * 4 + p) * 128 + hf * 64) * 8]); \
        } else { \
            const int p = (task - 16) >> 1, hf = task & 1; \
            const short* gsrc = FT2 + ((((size_t)b * KQ + (ks) * 4 + p) * SEQ) + s0 + hf * 64 + l) * 8; \
            gll16(gsrc, &Bs[buf][(p * 128 + hf * 64) * 8]); \
        } \
    } }

    f32x4 acc[2][4][4] = {};

    STAGE(0, 0);
    __syncthreads();                        // compiler drains vmcnt before barrier

    for (int ks = 0; ks < 16; ++ks) {
        const int cb = ks & 1;
        if (ks < 15) STAGE(ks + 1, cb ^ 1); // issue next-tile loads before ds_reads
        const short* Ab = &As[cb][0];
        const short* Bb = &Bs[cb][0];
        bf16x8 af[2][4], bfr[4];
        #pragma unroll
        for (int sl = 0; sl < 2; ++sl)
            #pragma unroll
            for (int i = 0; i < 4; ++i)
                af[sl][i] = *(const bf16x8*)&Ab[(((sl * 4 + quad) * 128) + wrow + i * 16 + ln) * 8];
        #pragma unroll
        for (int j = 0; j < 4; ++j)
            bfr[j] = *(const bf16x8*)&Bb[((size_t)quad * 128 + wcol + j * 16 + ln) * 8];
        #pragma unroll
        for (int sl = 0; sl < 2; ++sl)
            #pragma unroll
            for (int i = 0; i < 4; ++i)
                #pragma unroll
                for (int j = 0; j < 4; ++j)
                    acc[sl][i][j] = MFMA16(af[sl][i], bfr[j], acc[sl][i][j]);
        __syncthreads();
    }

    #pragma unroll
    for (int sl = 0; sl < 2; ++sl) {
        const int o0  = (yy + 6 * sl) * 128;
        const int sec = o0 >> 9;
        const int h   = (o0 >> 7) & 3;
        const size_t bh = (size_t)b * HEADS + h;

        if (sec == 0) {
            const float qs = 0.08838834764831845f * 1.4426950408889634f; // scale*log2(e)
            #pragma unroll
            for (int ti = 0; ti < 4; ++ti) {
                int d = wrow + ti * 16 + quad * 4;
                #pragma unroll
                for (int tj = 0; tj < 4; ++tj) {
                    int s = s0 + wcol + tj * 16 + ln;
                    f32x4 a = acc[sl][ti][tj];
                    bf16x4 pk4 = { f2bf(a[0]*qs), f2bf(a[1]*qs), f2bf(a[2]*qs), f2bf(a[3]*qs) };
                    *(bf16x4*)&Qo[(bh * SEQ + s) * DIMH + d] = pk4;
                }
            }
        } else if (sec == 1) {
            #pragma unroll
            for (int ti = 0; ti < 4; ++ti) {
                int d = wrow + ti * 16 + quad * 4;
                #pragma unroll
                for (int tj = 0; tj < 4; ++tj) {
                    int s = s0 + wcol + tj * 16 + ln;
                    float4 hv = *(const float4*)&height[(size_t)(s >> 5) * DIMH + d];
                    float4 wv = *(const float4*)&width[(size_t)(s & 31) * DIMH + d];
                    f32x4 a = acc[sl][ti][tj];
                    bf16x4 pk4 = { f2bf(a[0] + hv.x + wv.x), f2bf(a[1] + hv.y + wv.y),
                                   f2bf(a[2] + hv.z + wv.z), f2bf(a[3] + hv.w + wv.w) };
                    *(bf16x4*)&Kfo[(((size_t)bh * 16 + (d >> 3)) * SEQ + s) * 8 + (d & 7)] = pk4;
                }
            }
        } else {
            const int slot = ((ln >> 2) & 1) * 8 + (ln & 3) + ((ln >> 3) << 2);
            #pragma unroll
            for (int ti = 0; ti < 4; ++ti) {
                int d = wrow + ti * 16 + quad * 4;
                #pragma unroll
                for (int tj = 0; tj < 4; ++tj) {
                    int s = s0 + wcol + tj * 16 + ln;
                    size_t vb = (((size_t)bh * 64 + (s >> 4)) * DIMH) * 16 + slot;
                    f32x4 a = acc[sl][ti][tj];
                    #pragma unroll
                    for (int r = 0; r < 4; ++r)
                        Vfo[vb + (size_t)(d + r) * 16] = f2bf(a[r]);
                }
            }
        }
    }
}

// ---------- flash attention: quad-buffered K, stage distance +3, barrier per 2 tiles ----------
#define BQ 128
#define BJ 64
#define KSTR 136   // conflict-free stride (SQ_LDS_BANK_CONFLICT = 0)

// entry invariant at iter ti: S0/S1 = S(ti); slots hold K(ti+1), K(ti+2), K(ti+3*)
#define ATTN_ITER(ti, DO_QK, DO_PRE, DO_BAR)                                        \
{                                                                                   \
    const int rd = (((ti) + 1) & 3) * (BJ * KSTR);                                  \
    const int wr = (((ti) + 3) & 3) * (BJ * KSTR);                                  \
    const short* vp0 = Vlane + (size_t)((ti) * 4) * (DIMH * 16);                    \
    bf16x8 vr[4][4];                                                                \
    _Pragma("unroll") for (int gi = 0; gi < 2; ++gi)                                \
      _Pragma("unroll") for (int dc = 0; dc < 4; ++dc)                              \
        vr[gi][dc] = *(const bf16x8*)(vp0 + (size_t)gi * (DIMH * 16) + dc * 32 * 16);\
    int4 kreg[4];                                                                   \
    if (DO_PRE) {                                                                   \
        _Pragma("unroll") for (int p = 0; p < 4; ++p)                               \
            kreg[p] = *(const int4*)(Kg + ((size_t)(p * 4 + w) * SEQ + ((ti) + 3) * BJ + l) * 8); \
    }                                                                               \
    PF8 pf[4];                                                                      \
    _Pragma("unroll") for (int g = 0; g < 4; ++g) {                                 \
        const f32x16& Sh = (g & 2) ? S1 : S0;                                       \
        const int kk = g & 1;                                                       \
        _Pragma("unroll") for (int mm = 0; mm < 4; ++mm) {                          \
            float ea = __builtin_amdgcn_exp2f(Sh[kk * 8 + 2 * mm]);                 \
            float eb = __builtin_amdgcn_exp2f(Sh[kk * 8 + 2 * mm + 1]);             \
            psum += ea + eb;                                                        \
            pf[g].u[mm] = pk2(ea, eb);                                              \
        }                                                                           \
    }                                                                               \
    _Pragma("unroll") for (int gi = 2; gi < 4; ++gi)                                \
      _Pragma("unroll") for (int dc = 0; dc < 4; ++dc)                              \
        vr[gi][dc] = *(const bf16x8*)(vp0 + (size_t)gi * (DIMH * 16) + dc * 32 * 16);\
    if (DO_QK) {                                                                    \
        S0 = (f32x16){}; S1 = (f32x16){};                                           \
        _Pragma("unroll") for (int kc = 0; kc < 8; ++kc) {                          \
            bf16x8 k0 = *(const bf16x8*)&Ks[rd + c31 * KSTR + kc * 16 + h * 8];     \
            bf16x8 k1 = *(const bf16x8*)&Ks[rd + (32 + c31) * KSTR + kc * 16 + h * 8]; \
            S0 = MFMA32(k0, qf[kc], S0);                                            \
            S1 = MFMA32(k1, qf[kc], S1);                                            \
        }                                                                           \
    }                                                                               \
    _Pragma("unroll") for (int g = 0; g < 4; ++g)                                   \
        _Pragma("unroll") for (int dc = 0; dc < 4; ++dc)                            \
            O[dc] = MFMA32(vr[g][dc], pf[g].v, O[dc]);                              \
    if (DO_PRE) {                                                                   \
        _Pragma("unroll") for (int p = 0; p < 4; ++p)                               \
            *(int4*)&Ks[wr + l * KSTR + (p * 4 + w) * 8] = kreg[p];                 \
    }                                                                               \
    if (DO_BAR) __syncthreads();                                                    \
}

__global__ __launch_bounds__(256, 2) void attn(
    const short* __restrict__ Q, const short* __restrict__ Kf,
    const short* __restrict__ Vf, float* __restrict__ out)
{
    __shared__ short Ks[4 * BJ * KSTR];   // quad-buffered K tiles [j][c]

    const int t = threadIdx.x, l = t & 63, w = t >> 6;
    const int h = l >> 5, c31 = l & 31;

    const int L = blockIdx.x;
    const int x = L & 7, inner = L >> 3;          // XCD swizzle: same bh -> same XCD
    const int bh = x * 8 + (inner >> 3);
    const int q0 = (inner & 7) * BQ;
    const size_t obase = (size_t)bh * DIMH * SEQ;

    // Q B-fragments (n = i = q0+w*32+c31, k = c = kc*16 + h*8 + 0..7)
    bf16x8 qf[8];
    {
        const short* Qp = Q + ((size_t)bh * SEQ + (q0 + w * 32 + c31)) * DIMH + h * 8;
        #pragma unroll
        for (int kc = 0; kc < 8; ++kc)
            qf[kc] = *(const bf16x8*)(Qp + kc * 16);
    }

    const short* Kg = Kf + (size_t)bh * 16 * SEQ * 8;             // [cg][s][8]
    const short* Vlane = Vf + (size_t)bh * 64 * (DIMH * 16) + (c31 * 16 + h * 8);

    f32x16 O[4] = {};
    float psum = 0.f;

    // prologue: stage K(0)->slot0, K(1)->slot1, K(2)->slot2
    {
        int4 k0[4], k1[4], k2[4];
        #pragma unroll
        for (int p = 0; p < 4; ++p) {
            k0[p] = *(const int4*)(Kg + ((size_t)(p * 4 + w) * SEQ + l) * 8);
            k1[p] = *(const int4*)(Kg + ((size_t)(p * 4 + w) * SEQ + BJ + l) * 8);
            k2[p] = *(const int4*)(Kg + ((size_t)(p * 4 + w) * SEQ + 2 * BJ + l) * 8);
        }
        #pragma unroll
        for (int p = 0; p < 4; ++p) {
            *(int4*)&Ks[l * KSTR + (p * 4 + w) * 8] = k0[p];
            *(int4*)&Ks[1 * (BJ * KSTR) + l * KSTR + (p * 4 + w) * 8] = k1[p];
            *(int4*)&Ks[2 * (BJ * KSTR) + l * KSTR + (p * 4 + w) * 8] = k2[p];
        }
    }
    __syncthreads();

    // S(0) from slot0
    f32x16 S0 = {}, S1 = {};
    #pragma unroll
    for (int kc = 0; kc < 8; ++kc) {
        bf16x8 k0 = *(const bf16x8*)&Ks[c31 * KSTR + kc * 16 + h * 8];
        bf16x8 k1 = *(const bf16x8*)&Ks[(32 + c31) * KSTR + kc * 16 + h * 8];
        S0 = MFMA32(k0, qf[kc], S0);
        S1 = MFMA32(k1, qf[kc], S1);
    }
    __syncthreads();   // all waves done reading slot0 before iter1 overwrites it

    // iters 0..11: full pipeline, barrier at end of odd iters only
    for (int p = 0; p < 6; ++p) {
        const int t0 = 2 * p;
        ATTN_ITER(t0,     true, true, false);
        ATTN_ITER(t0 + 1, true, true, true);
    }
    ATTN_ITER(12, true, true,  false);   // stages K(15), last stage
    ATTN_ITER(13, true, false, true);    // barrier covers K(15) write -> read at 14
    ATTN_ITER(14, true, false, false);
    ATTN_ITER(15, false, false, false);

    // row sum: this lane holds half the j's for row i=c31; other half in lane^32
    psum += __shfl_xor(psum, 32);
    float linv = 1.0f / psum;

    #pragma unroll
    for (int dc = 0; dc < 4; ++dc)
        #pragma unroll
        for (int r = 0; r < 16; ++r) {
            int d = dc * 32 + (r & 3) + 8 * (r >> 2) + 4 * h;
            out[obase + (size_t)d * SEQ + q0 + w * 32 + c31] = O[dc][r] * linv;
        }
}

extern "C" void kernel_launch(void* const* d_in, const int* in_sizes, int n_in,
                              void* d_out, int out_size, void* d_ws, size_t ws_size,
                              hipStream_t stream) {
    const float* fmap   = (const float*)d_in[0];
    const float* w_qkv  = (const float*)d_in[1];
    const float* height = (const float*)d_in[2];
    const float* width  = (const float*)d_in[3];
    float* outp = (float*)d_out;

    const size_t n_ft  = (size_t)NB * SEQ * CIN;
    const size_t n_w   = (size_t)OTOT * CIN;
    const size_t n_qkv = (size_t)NB * HEADS * SEQ * DIMH;

    short* FT2 = (short*)d_ws;
    short* Wb2 = FT2 + n_ft;
    short* Qb  = Wb2 + n_w;
    short* Kfb = Qb + n_qkv;
    short* Vfb = Kfb + n_qkv;

    convert_all<<<dim3(6, KQ, NB + 1), 256, 0, stream>>>(fmap, w_qkv, FT2, Wb2);
    qkv_gemm<<<dim3(8 * 6 * NB), 256, 0, stream>>>(
        Wb2, FT2, height, width, Qb, Kfb, Vfb);
    attn<<<dim3(NB * HEADS * (SEQ / BQ)), 256, 0, stream>>>(Qb, Kfb, Vfb, outp);
}